// Round 3
// baseline (4124.841 us; speedup 1.0000x reference)
//
#include <hip/hip_runtime.h>
#include <hip/hip_bf16.h>
#include <stdint.h>

// Problem constants
#define Bb 16
#define Ss 2048
#define Dd 1024
#define Hh 1024
#define Rr 16
#define Mm 32768   // B*S

typedef __attribute__((ext_vector_type(4))) float f32x4;
typedef __attribute__((ext_vector_type(8))) short bf16x8;

// RNE fp32 -> bf16 bits
__device__ __forceinline__ unsigned short f2bf(float f) {
    union { float f; uint32_t u; } c; c.f = f;
    uint32_t u = c.u + 0x7fffu + ((c.u >> 16) & 1u);
    return (unsigned short)(u >> 16);
}
__device__ __forceinline__ float bfbits2f(uint32_t hi) {
    union { uint32_t u; float f; } c; c.u = hi << 16; return c.f;
}
__device__ __forceinline__ float bfhi2f(uint32_t masked) {
    union { uint32_t u; float f; } c; c.u = masked; return c.f;
}

// async global->LDS, 16B per lane. LDS dest = uniform base + lane*16.
__device__ __forceinline__ void gld16(const void* gsrc, void* ldst) {
    __builtin_amdgcn_global_load_lds(
        (const __attribute__((address_space(1))) unsigned int*)gsrc,
        (__attribute__((address_space(3))) unsigned int*)ldst, 16, 0, 0);
}

// Raw workgroup barrier WITHOUT the vmcnt(0) drain __syncthreads carries.
// lgkmcnt(0) makes LDS writes/atomics visible across waves; outstanding
// global (prefetch) loads stay in flight.
// imm 0xC07F = vmcnt(63) expcnt(7) lgkmcnt(0)  [gfx9 encoding]
__device__ __forceinline__ void softbar() {
    __asm volatile("" ::: "memory");
    __builtin_amdgcn_s_waitcnt(0xC07F);
    __builtin_amdgcn_s_barrier();
    __asm volatile("" ::: "memory");
}

// ---------------------------------------------------------------------------
// Kernel 1: convert x, Wa, Wu to bf16 (flat, 4 elems/thread)
// ---------------------------------------------------------------------------
__global__ __launch_bounds__(256) void k_convert(
    const float* __restrict__ x, const float* __restrict__ Wa,
    const float* __restrict__ Wu,
    unsigned short* __restrict__ xb, unsigned short* __restrict__ Wab,
    unsigned short* __restrict__ Wub)
{
    long e = ((long)blockIdx.x * 256 + threadIdx.x) * 4;
    const long nx = (long)Mm * Dd;        // 33,554,432
    const long nw = (long)Hh * Dd;        // 1,048,576
    const float* src; unsigned short* dst; long o;
    if (e < nx)            { src = x;  dst = xb;  o = e; }
    else if (e < nx + nw)  { src = Wa; dst = Wab; o = e - nx; }
    else                   { src = Wu; dst = Wub; o = e - nx - nw; }
    float4 f = *(const float4*)(src + o);
    ushort4 r;
    r.x = f2bf(f.x); r.y = f2bf(f.y); r.z = f2bf(f.z); r.w = f2bf(f.w);
    *(ushort4*)(dst + o) = r;
}

// ---------------------------------------------------------------------------
// Kernel 2: C[M,1024] = Xb @ W^T (+bias, optional sigmoid), bf16 MFMA.
// Outputs now bf16 (halves epilogue writes AND the scan's stream reads).
// ---------------------------------------------------------------------------
__global__ __launch_bounds__(256) void k_gemm(
    const unsigned short* __restrict__ Xb,   // [M, D] bf16 bits
    const unsigned short* __restrict__ Wab,  // [H, D]
    const unsigned short* __restrict__ Wub,  // [H, D]
    const float* __restrict__ ba, const float* __restrict__ bu,
    unsigned short* __restrict__ outA, unsigned short* __restrict__ outU)
{
    __shared__ short At[128 * 32];
    __shared__ short Bt[128 * 32];

    const int tid  = threadIdx.x;
    const int lane = tid & 63;
    const int wave = tid >> 6;
    const int bm = blockIdx.x;
    const int bn = blockIdx.y;
    const int region = bn >> 3;            // 0: a, 1: u_in
    const int nbase = (bn & 7) * 128;

    const short* Ag = (const short*)Xb;
    const short* Bg = (const short*)(region ? Wub : Wab);
    const float* bias = region ? bu : ba;
    unsigned short* outp = region ? outU : outA;

    const int wm = wave & 1, wn = wave >> 1;
    const int srow = lane >> 2, sseg = lane & 3;   // staging: 4 lanes/row
    const int mrow = lane & 15, kb = lane >> 4;    // fragment lane mapping

    f32x4 acc[4][4] = {};

    for (int kt = 0; kt < 32; ++kt) {
        __syncthreads();
        const int k0 = kt * 32;
        #pragma unroll
        for (int p = 0; p < 2; ++p) {
            const int row = p * 64 + wave * 16 + srow;
            const short* ga = Ag + (long)(bm * 128 + row) * Dd + k0 + sseg * 8;
            gld16((const void*)ga, (void*)&At[p * 2048 + wave * 512]);
            const short* gb = Bg + (long)(nbase + row) * Dd + k0 + sseg * 8;
            gld16((const void*)gb, (void*)&Bt[p * 2048 + wave * 512]);
        }
        __syncthreads();

        bf16x8 af[4], bq[4];
        #pragma unroll
        for (int i = 0; i < 4; ++i) {
            af[i] = *(const bf16x8*)&At[(wm * 64 + i * 16 + mrow) * 32 + kb * 8];
            bq[i] = *(const bf16x8*)&Bt[(wn * 64 + i * 16 + mrow) * 32 + kb * 8];
        }
        #pragma unroll
        for (int i = 0; i < 4; ++i)
            #pragma unroll
            for (int j = 0; j < 4; ++j)
                acc[i][j] = __builtin_amdgcn_mfma_f32_16x16x32_bf16(
                    af[i], bq[j], acc[i][j], 0, 0, 0);
    }

    // Epilogue: C/D layout col=lane&15, row=(lane>>4)*4+reg (m89-verified)
    const int col = lane & 15, rq = lane >> 4;
    #pragma unroll
    for (int j = 0; j < 4; ++j) {
        const int n = nbase + wn * 64 + j * 16 + col;
        const float bv = bias[n];
        #pragma unroll
        for (int i = 0; i < 4; ++i) {
            const int mb = bm * 128 + wm * 64 + i * 16 + rq * 4;
            #pragma unroll
            for (int r = 0; r < 4; ++r) {
                float vv = acc[i][j][r] + bv;
                if (region == 0) vv = 1.0f / (1.0f + __expf(-vv));
                outp[(long)(mb + r) * Hh + n] = f2bf(vv);
            }
        }
    }
}

// ---------------------------------------------------------------------------
// Kernel 3: g[M,16] = x @ Wg^T + bg (fp32, tiny N)
// ---------------------------------------------------------------------------
__global__ __launch_bounds__(256) void k_g(
    const float* __restrict__ x, const float* __restrict__ Wg,
    const float* __restrict__ bg, float* __restrict__ g)
{
    const int tid = threadIdx.x;
    const int r = tid & 15, ml = tid >> 4;
    const long m = (long)blockIdx.x * 16 + ml;
    const float4* xr = (const float4*)(x + m * Dd);
    const float4* wr = (const float4*)(Wg + (long)r * Dd);
    float acc = 0.0f;
    #pragma unroll 4
    for (int k = 0; k < Dd / 4; ++k) {
        float4 a = xr[k], b = wr[k];
        acc = fmaf(a.x, b.x, acc); acc = fmaf(a.y, b.y, acc);
        acc = fmaf(a.z, b.z, acc); acc = fmaf(a.w, b.w, acc);
    }
    g[m * Rr + r] = acc + bg[r];
}

// ---------------------------------------------------------------------------
// Kernel 4: sequential scan. One block per b (16 blocks x 1024 threads).
// NO shuffle tree (R2's 6 dependent ds_swizzle hops ~= 700 cyc/step):
//  phase 1: thread (hb=tid>>4, m=tid&15) computes partial of r=m over
//           h in [16hb,16hb+16) from bf16 state in LDS (16-lane broadcast
//           reads), scales by g_t[m], ONE ds_add_f32 into cacc[par][m].
//  phase 2: thread owns h=tid: s = a*s + u + sum_r q[r]*U[h][r], q read
//           as 4x b128 broadcast from summed cacc.
// cacc double-buffered: step t uses cacc[t&1], zeroes cacc[(t+1)&1].
// softbar (no vmcnt drain) keeps the depth-4 global prefetch ring in
// flight across step boundaries. a/u streams are bf16.
// ---------------------------------------------------------------------------
__global__ __launch_bounds__(1024) void k_scan(
    const unsigned short* __restrict__ a,    // [B,S,H] bf16
    const unsigned short* __restrict__ uin,  // [B,S,H] bf16
    const float* __restrict__ g,    // [B,S,R]
    const float* __restrict__ u,    // [H,R]
    const float* __restrict__ v,    // [H,R]
    float* __restrict__ out)        // [B,H]
{
    __shared__ __align__(16) unsigned short sb[Hh];  // bf16 state, 2 KB
    __shared__ __align__(16) float cacc[2][16];

    const int tid = threadIdx.x;
    const int m  = tid & 15;     // r index (phase 1 partial, g column)
    const int hb = tid >> 4;     // h block [0,64)
    const int b = blockIdx.x;

    // phase-2 consts: U row for h = tid
    float ur[16];
    #pragma unroll
    for (int j = 0; j < 4; ++j) {
        float4 t4 = *(const float4*)&u[tid * Rr + j * 4];
        ur[j*4+0] = t4.x; ur[j*4+1] = t4.y; ur[j*4+2] = t4.z; ur[j*4+3] = t4.w;
    }
    // phase-1 consts: v[16*hb + j][m]
    float vr[16];
    #pragma unroll
    for (int j = 0; j < 16; ++j) vr[j] = v[(hb * 16 + j) * Rr + m];

    const unsigned short* ap = a   + (long)b * Ss * Hh + tid;
    const unsigned short* up = uin + (long)b * Ss * Hh + tid;
    const float*          gp = g   + (long)b * Ss * Rr + m;

    float s = 0.0f;
    uint32_t pa[4], pu[4]; float pg[4];
    #pragma unroll
    for (int t = 0; t < 4; ++t) {
        pa[t] = ap[t * Hh]; pu[t] = up[t * Hh]; pg[t] = gp[t * Rr];
    }
    ap += 4 * Hh; up += 4 * Hh; gp += 4 * Rr;

    // init state + both accumulator buffers
    sb[tid] = 0;
    if (tid < 32) ((float*)cacc)[tid] = 0.0f;
    __syncthreads();

    const unsigned short* srow = sb + hb * 16;

#define STEP(R, PF, PAR) do {                                               \
    /* phase 1: partial_r = g_t[m] * sum_{16h} s[h]*v[h][m] */              \
    uint4 w0 = *(const uint4*)(srow);                                       \
    uint4 w1 = *((const uint4*)(srow) + 1);                                 \
    float part = 0.0f;                                                      \
    part = fmaf(bfbits2f(w0.x & 0xffffu), vr[0], part);                     \
    part = fmaf(bfhi2f(w0.x & 0xffff0000u), vr[1], part);                   \
    part = fmaf(bfbits2f(w0.y & 0xffffu), vr[2], part);                     \
    part = fmaf(bfhi2f(w0.y & 0xffff0000u), vr[3], part);                   \
    part = fmaf(bfbits2f(w0.z & 0xffffu), vr[4], part);                     \
    part = fmaf(bfhi2f(w0.z & 0xffff0000u), vr[5], part);                   \
    part = fmaf(bfbits2f(w0.w & 0xffffu), vr[6], part);                     \
    part = fmaf(bfhi2f(w0.w & 0xffff0000u), vr[7], part);                   \
    part = fmaf(bfbits2f(w1.x & 0xffffu), vr[8], part);                     \
    part = fmaf(bfhi2f(w1.x & 0xffff0000u), vr[9], part);                   \
    part = fmaf(bfbits2f(w1.y & 0xffffu), vr[10], part);                    \
    part = fmaf(bfhi2f(w1.y & 0xffff0000u), vr[11], part);                  \
    part = fmaf(bfbits2f(w1.z & 0xffffu), vr[12], part);                    \
    part = fmaf(bfhi2f(w1.z & 0xffff0000u), vr[13], part);                  \
    part = fmaf(bfbits2f(w1.w & 0xffffu), vr[14], part);                    \
    part = fmaf(bfhi2f(w1.w & 0xffff0000u), vr[15], part);                  \
    part *= pg[R];                                                          \
    unsafeAtomicAdd(&cacc[PAR][m], part);                                   \
    if (tid < 16) cacc[PAR ^ 1][tid] = 0.0f;                                \
    softbar(); /* bar1: all atomics drained (lgkmcnt) */                    \
    /* phase 2: s = a*s + u + sum_r q[r]*U[h][r] */                         \
    f32x4 q0 = *(const f32x4*)&cacc[PAR][0];                                \
    f32x4 q1 = *(const f32x4*)&cacc[PAR][4];                                \
    f32x4 q2 = *(const f32x4*)&cacc[PAR][8];                                \
    f32x4 q3 = *(const f32x4*)&cacc[PAR][12];                               \
    float lr = 0.0f;                                                        \
    lr = fmaf(q0.x, ur[0],  lr); lr = fmaf(q0.y, ur[1],  lr);               \
    lr = fmaf(q0.z, ur[2],  lr); lr = fmaf(q0.w, ur[3],  lr);               \
    lr = fmaf(q1.x, ur[4],  lr); lr = fmaf(q1.y, ur[5],  lr);               \
    lr = fmaf(q1.z, ur[6],  lr); lr = fmaf(q1.w, ur[7],  lr);               \
    lr = fmaf(q2.x, ur[8],  lr); lr = fmaf(q2.y, ur[9],  lr);               \
    lr = fmaf(q2.z, ur[10], lr); lr = fmaf(q2.w, ur[11], lr);               \
    lr = fmaf(q3.x, ur[12], lr); lr = fmaf(q3.y, ur[13], lr);               \
    lr = fmaf(q3.z, ur[14], lr); lr = fmaf(q3.w, ur[15], lr);               \
    s = fmaf(bfbits2f(pa[R]), s, bfbits2f(pu[R]) + lr);                     \
    { union { float f; uint32_t uu; } cv; cv.f = s;                         \
      sb[tid] = (unsigned short)(cv.uu >> 16); }     /* RTZ pack */         \
    if (PF) {                                                               \
        pa[R] = *ap; ap += Hh;                                              \
        pu[R] = *up; up += Hh;                                              \
        pg[R] = *gp; gp += Rr;                                              \
    }                                                                       \
    softbar(); /* bar2: s visible for next step's phase 1 */                \
} while (0)

    for (int t4 = 0; t4 < Ss / 4 - 1; ++t4) {
        STEP(0, 1, 0); STEP(1, 1, 1); STEP(2, 1, 0); STEP(3, 1, 1);
    }
    STEP(0, 0, 0); STEP(1, 0, 1); STEP(2, 0, 0); STEP(3, 0, 1);
#undef STEP

    out[(long)b * Hh + tid] = s;
}

// ---------------------------------------------------------------------------
extern "C" void kernel_launch(void* const* d_in, const int* in_sizes, int n_in,
                              void* d_out, int out_size, void* d_ws, size_t ws_size,
                              hipStream_t stream)
{
    const float* x  = (const float*)d_in[0];
    const float* Wa = (const float*)d_in[1];
    const float* ba = (const float*)d_in[2];
    const float* Wg = (const float*)d_in[3];
    const float* bg = (const float*)d_in[4];
    const float* Wu = (const float*)d_in[5];
    const float* bu = (const float*)d_in[6];
    const float* u  = (const float*)d_in[7];
    const float* v  = (const float*)d_in[8];
    float* out = (float*)d_out;

    char* ws = (char*)d_ws;
    unsigned short* xb   = (unsigned short*)(ws);                // 67,108,864 B
    unsigned short* Wab  = (unsigned short*)(ws + 67108864);     //  2,097,152 B
    unsigned short* Wub  = (unsigned short*)(ws + 69206016);     //  2,097,152 B
    unsigned short* abuf = (unsigned short*)(ws + 71303168);     // 67,108,864 B (bf16)
    unsigned short* ubuf = (unsigned short*)(ws + 138412032);    // 67,108,864 B (bf16)
    float*          gbuf = (float*)(ws + 205520896);             //  2,097,152 B

    hipLaunchKernelGGL(k_convert, dim3(34816), dim3(256), 0, stream,
                       x, Wa, Wu, xb, Wab, Wub);
    hipLaunchKernelGGL(k_gemm, dim3(256, 16), dim3(256), 0, stream,
                       xb, Wab, Wub, ba, bu, abuf, ubuf);
    hipLaunchKernelGGL(k_g, dim3(2048), dim3(256), 0, stream,
                       x, Wg, bg, gbuf);
    hipLaunchKernelGGL(k_scan, dim3(Bb), dim3(1024), 0, stream,
                       abuf, ubuf, gbuf, u, v, out);
}

// Round 4
// 1913.244 us; speedup vs baseline: 2.1559x; 2.1559x over previous
//
#include <hip/hip_runtime.h>
#include <hip/hip_bf16.h>
#include <stdint.h>

// Problem constants
#define Bb 16
#define Ss 2048
#define Dd 1024
#define Hh 1024
#define Rr 16
#define Mm 32768   // B*S

typedef __attribute__((ext_vector_type(4))) float f32x4;
typedef __attribute__((ext_vector_type(8))) short bf16x8;

// RNE fp32 -> bf16 bits
__device__ __forceinline__ unsigned short f2bf(float f) {
    union { float f; uint32_t u; } c; c.f = f;
    uint32_t u = c.u + 0x7fffu + ((c.u >> 16) & 1u);
    return (unsigned short)(u >> 16);
}
__device__ __forceinline__ float bfbits2f(uint32_t bits) {
    union { uint32_t u; float f; } c; c.u = bits << 16; return c.f;
}

// async global->LDS, 16B per lane. LDS dest = uniform base + lane*16.
__device__ __forceinline__ void gld16(const void* gsrc, void* ldst) {
    __builtin_amdgcn_global_load_lds(
        (const __attribute__((address_space(1))) unsigned int*)gsrc,
        (__attribute__((address_space(3))) unsigned int*)ldst, 16, 0, 0);
}

// Raw workgroup barrier WITHOUT the vmcnt(0) drain __syncthreads carries.
// lgkmcnt(0) makes LDS writes visible across waves; outstanding global
// (prefetch) loads stay in flight. Proven in R2: scan 2676 -> 1380 us.
// imm 0xC07F = vmcnt(63) expcnt(7) lgkmcnt(0)  [gfx9 encoding]
__device__ __forceinline__ void softbar() {
    __asm volatile("" ::: "memory");
    __builtin_amdgcn_s_waitcnt(0xC07F);
    __builtin_amdgcn_s_barrier();
    __asm volatile("" ::: "memory");
}

// ---------------------------------------------------------------------------
// Kernel 1: convert x, Wa, Wu to bf16 (flat, 4 elems/thread)
// ---------------------------------------------------------------------------
__global__ __launch_bounds__(256) void k_convert(
    const float* __restrict__ x, const float* __restrict__ Wa,
    const float* __restrict__ Wu,
    unsigned short* __restrict__ xb, unsigned short* __restrict__ Wab,
    unsigned short* __restrict__ Wub)
{
    long e = ((long)blockIdx.x * 256 + threadIdx.x) * 4;
    const long nx = (long)Mm * Dd;        // 33,554,432
    const long nw = (long)Hh * Dd;        // 1,048,576
    const float* src; unsigned short* dst; long o;
    if (e < nx)            { src = x;  dst = xb;  o = e; }
    else if (e < nx + nw)  { src = Wa; dst = Wab; o = e - nx; }
    else                   { src = Wu; dst = Wub; o = e - nx - nw; }
    float4 f = *(const float4*)(src + o);
    ushort4 r;
    r.x = f2bf(f.x); r.y = f2bf(f.y); r.z = f2bf(f.z); r.w = f2bf(f.w);
    *(ushort4*)(dst + o) = r;
}

// ---------------------------------------------------------------------------
// Kernel 2: C[M,1024] = Xb @ W^T (+bias, optional sigmoid), bf16 MFMA.
// Outputs bf16 (halves epilogue writes AND the scan's stream reads).
// ---------------------------------------------------------------------------
__global__ __launch_bounds__(256) void k_gemm(
    const unsigned short* __restrict__ Xb,   // [M, D] bf16 bits
    const unsigned short* __restrict__ Wab,  // [H, D]
    const unsigned short* __restrict__ Wub,  // [H, D]
    const float* __restrict__ ba, const float* __restrict__ bu,
    unsigned short* __restrict__ outA, unsigned short* __restrict__ outU)
{
    __shared__ short At[128 * 32];
    __shared__ short Bt[128 * 32];

    const int tid  = threadIdx.x;
    const int lane = tid & 63;
    const int wave = tid >> 6;
    const int bm = blockIdx.x;
    const int bn = blockIdx.y;
    const int region = bn >> 3;            // 0: a, 1: u_in
    const int nbase = (bn & 7) * 128;

    const short* Ag = (const short*)Xb;
    const short* Bg = (const short*)(region ? Wub : Wab);
    const float* bias = region ? bu : ba;
    unsigned short* outp = region ? outU : outA;

    const int wm = wave & 1, wn = wave >> 1;
    const int srow = lane >> 2, sseg = lane & 3;   // staging: 4 lanes/row
    const int mrow = lane & 15, kb = lane >> 4;    // fragment lane mapping

    f32x4 acc[4][4] = {};

    for (int kt = 0; kt < 32; ++kt) {
        __syncthreads();
        const int k0 = kt * 32;
        #pragma unroll
        for (int p = 0; p < 2; ++p) {
            const int row = p * 64 + wave * 16 + srow;
            const short* ga = Ag + (long)(bm * 128 + row) * Dd + k0 + sseg * 8;
            gld16((const void*)ga, (void*)&At[p * 2048 + wave * 512]);
            const short* gb = Bg + (long)(nbase + row) * Dd + k0 + sseg * 8;
            gld16((const void*)gb, (void*)&Bt[p * 2048 + wave * 512]);
        }
        __syncthreads();

        bf16x8 af[4], bq[4];
        #pragma unroll
        for (int i = 0; i < 4; ++i) {
            af[i] = *(const bf16x8*)&At[(wm * 64 + i * 16 + mrow) * 32 + kb * 8];
            bq[i] = *(const bf16x8*)&Bt[(wn * 64 + i * 16 + mrow) * 32 + kb * 8];
        }
        #pragma unroll
        for (int i = 0; i < 4; ++i)
            #pragma unroll
            for (int j = 0; j < 4; ++j)
                acc[i][j] = __builtin_amdgcn_mfma_f32_16x16x32_bf16(
                    af[i], bq[j], acc[i][j], 0, 0, 0);
    }

    // Epilogue: C/D layout col=lane&15, row=(lane>>4)*4+reg (m89-verified)
    const int col = lane & 15, rq = lane >> 4;
    #pragma unroll
    for (int j = 0; j < 4; ++j) {
        const int n = nbase + wn * 64 + j * 16 + col;
        const float bv = bias[n];
        #pragma unroll
        for (int i = 0; i < 4; ++i) {
            const int mb = bm * 128 + wm * 64 + i * 16 + rq * 4;
            #pragma unroll
            for (int r = 0; r < 4; ++r) {
                float vv = acc[i][j][r] + bv;
                if (region == 0) vv = 1.0f / (1.0f + __expf(-vv));
                outp[(long)(mb + r) * Hh + n] = f2bf(vv);
            }
        }
    }
}

// ---------------------------------------------------------------------------
// Kernel 3: g[M,16] = x @ Wg^T + bg (fp32, tiny N)
// ---------------------------------------------------------------------------
__global__ __launch_bounds__(256) void k_g(
    const float* __restrict__ x, const float* __restrict__ Wg,
    const float* __restrict__ bg, float* __restrict__ g)
{
    const int tid = threadIdx.x;
    const int r = tid & 15, ml = tid >> 4;
    const long m = (long)blockIdx.x * 16 + ml;
    const float4* xr = (const float4*)(x + m * Dd);
    const float4* wr = (const float4*)(Wg + (long)r * Dd);
    float acc = 0.0f;
    #pragma unroll 4
    for (int k = 0; k < Dd / 4; ++k) {
        float4 a = xr[k], b = wr[k];
        acc = fmaf(a.x, b.x, acc); acc = fmaf(a.y, b.y, acc);
        acc = fmaf(a.z, b.z, acc); acc = fmaf(a.w, b.w, acc);
    }
    g[m * Rr + r] = acc + bg[r];
}

// ---------------------------------------------------------------------------
// Kernel 4: sequential scan. One block per b (16 blocks x 1024 threads).
// 3-phase shallow reduction (NO deep shuffle tree, NO LDS atomics — R3
// showed >=16-way same-address ds_add serializes ~2000 cyc/step):
//  A: wave w covers h in [64w,64w+64); lane: 16 FMAs for r=lane&15 over
//     its 16-h sub-block (sub=lane>>4), then 2 shuffle hops (xor16,32);
//     lanes<16 write partial -> cacc[r][w].
//  B: wave 0 lanes<16: sum 16 wave-partials of row r, scale by g_t[r],
//     write qbuf[r].
//  C: thread owns h=tid: q broadcast, 16 FMAs, s=a*s+u+lr, write state.
// fp32 state in LDS (no unpack VALU). a/u streams bf16. softbar keeps the
// depth-4 global prefetch ring in flight across all barriers.
// ---------------------------------------------------------------------------
__global__ __launch_bounds__(1024) void k_scan(
    const unsigned short* __restrict__ a,    // [B,S,H] bf16
    const unsigned short* __restrict__ uin,  // [B,S,H] bf16
    const float* __restrict__ g,    // [B,S,R]
    const float* __restrict__ u,    // [H,R]
    const float* __restrict__ v,    // [H,R]
    float* __restrict__ out)        // [B,H]
{
    __shared__ __align__(16) float sbf[Hh];        // fp32 state, 4 KB
    __shared__ __align__(16) float cacc[16 * 20];  // [r][w], stride 20
    __shared__ __align__(16) float qbuf[16];

    const int tid  = threadIdx.x;
    const int lane = tid & 63;
    const int wave = tid >> 6;
    const int sub  = lane >> 4;      // h sub-block within wave
    const int ra   = lane & 15;      // r owned in phase A
    const int b = blockIdx.x;

    // phase-A consts: v[64w + 16*sub + j][ra]
    const int hA = wave * 64 + sub * 16;
    float vr[16];
    #pragma unroll
    for (int j = 0; j < 16; ++j) vr[j] = v[(hA + j) * Rr + ra];
    // phase-C consts: U row for h = tid
    float ur[16];
    #pragma unroll
    for (int j = 0; j < 4; ++j) {
        float4 t4 = *(const float4*)&u[tid * Rr + j * 4];
        ur[j*4+0] = t4.x; ur[j*4+1] = t4.y; ur[j*4+2] = t4.z; ur[j*4+3] = t4.w;
    }

    const unsigned short* ap = a   + (long)b * Ss * Hh + tid;
    const unsigned short* up = uin + (long)b * Ss * Hh + tid;
    const float*          gp = g   + (long)b * Ss * Rr + tid;  // tid<16 only

    float s = 0.0f;
    uint32_t pa[4], pu[4]; float pg[4];
    #pragma unroll
    for (int t = 0; t < 4; ++t) { pa[t] = ap[t * Hh]; pu[t] = up[t * Hh]; }
    ap += 4 * Hh; up += 4 * Hh;
    if (tid < 16) {
        #pragma unroll
        for (int t = 0; t < 4; ++t) pg[t] = gp[t * Rr];
        gp += 4 * Rr;
    }

    sbf[tid] = 0.0f;
    __syncthreads();

    const float* spA = &sbf[hA];

#define STEP(R, PF) do {                                                    \
    /* A: partial_{r=ra} over 16 h's */                                     \
    f32x4 s0 = *(const f32x4*)(spA);                                        \
    f32x4 s1 = *((const f32x4*)(spA) + 1);                                  \
    f32x4 s2 = *((const f32x4*)(spA) + 2);                                  \
    f32x4 s3 = *((const f32x4*)(spA) + 3);                                  \
    float part = s0.x * vr[0];                                              \
    part = fmaf(s0.y, vr[1],  part); part = fmaf(s0.z, vr[2],  part);       \
    part = fmaf(s0.w, vr[3],  part); part = fmaf(s1.x, vr[4],  part);       \
    part = fmaf(s1.y, vr[5],  part); part = fmaf(s1.z, vr[6],  part);       \
    part = fmaf(s1.w, vr[7],  part); part = fmaf(s2.x, vr[8],  part);       \
    part = fmaf(s2.y, vr[9],  part); part = fmaf(s2.z, vr[10], part);       \
    part = fmaf(s2.w, vr[11], part); part = fmaf(s3.x, vr[12], part);       \
    part = fmaf(s3.y, vr[13], part); part = fmaf(s3.z, vr[14], part);       \
    part = fmaf(s3.w, vr[15], part);                                        \
    part += __shfl_xor(part, 16);                                           \
    part += __shfl_xor(part, 32);                                           \
    if (lane < 16) cacc[20 * ra + wave] = part;                             \
    softbar(); /* bar1 */                                                   \
    /* B: q[r] = g_t[r] * sum_w cacc[r][w]  (wave 0, lanes<16) */           \
    if (tid < 16) {                                                         \
        const float* cr = &cacc[20 * tid];                                  \
        f32x4 c0 = *(const f32x4*)(cr);                                     \
        f32x4 c1 = *((const f32x4*)(cr) + 1);                               \
        f32x4 c2 = *((const f32x4*)(cr) + 2);                               \
        f32x4 c3 = *((const f32x4*)(cr) + 3);                               \
        f32x4 cs = (c0 + c1) + (c2 + c3);                                   \
        qbuf[tid] = pg[R] * ((cs.x + cs.y) + (cs.z + cs.w));                \
        if (PF) { pg[R] = *gp; gp += Rr; }                                  \
    }                                                                       \
    softbar(); /* bar2 */                                                   \
    /* C: s = a*s + u + sum_r q[r]*U[h][r] */                               \
    f32x4 q0 = *(const f32x4*)(qbuf);                                       \
    f32x4 q1 = *((const f32x4*)(qbuf) + 1);                                 \
    f32x4 q2 = *((const f32x4*)(qbuf) + 2);                                 \
    f32x4 q3 = *((const f32x4*)(qbuf) + 3);                                 \
    float lr = q0.x * ur[0];                                                \
    lr = fmaf(q0.y, ur[1],  lr); lr = fmaf(q0.z, ur[2],  lr);               \
    lr = fmaf(q0.w, ur[3],  lr); lr = fmaf(q1.x, ur[4],  lr);               \
    lr = fmaf(q1.y, ur[5],  lr); lr = fmaf(q1.z, ur[6],  lr);               \
    lr = fmaf(q1.w, ur[7],  lr); lr = fmaf(q2.x, ur[8],  lr);               \
    lr = fmaf(q2.y, ur[9],  lr); lr = fmaf(q2.z, ur[10], lr);               \
    lr = fmaf(q2.w, ur[11], lr); lr = fmaf(q3.x, ur[12], lr);               \
    lr = fmaf(q3.y, ur[13], lr); lr = fmaf(q3.z, ur[14], lr);               \
    lr = fmaf(q3.w, ur[15], lr);                                            \
    s = fmaf(bfbits2f(pa[R]), s, bfbits2f(pu[R]) + lr);                     \
    sbf[tid] = s;                                                           \
    if (PF) {                                                               \
        pa[R] = *ap; ap += Hh;                                              \
        pu[R] = *up; up += Hh;                                              \
    }                                                                       \
    softbar(); /* bar3 */                                                   \
} while (0)

    for (int t4 = 0; t4 < Ss / 4 - 1; ++t4) {
        STEP(0, 1); STEP(1, 1); STEP(2, 1); STEP(3, 1);
    }
    STEP(0, 0); STEP(1, 0); STEP(2, 0); STEP(3, 0);
#undef STEP

    out[(long)b * Hh + tid] = s;
}

// ---------------------------------------------------------------------------
extern "C" void kernel_launch(void* const* d_in, const int* in_sizes, int n_in,
                              void* d_out, int out_size, void* d_ws, size_t ws_size,
                              hipStream_t stream)
{
    const float* x  = (const float*)d_in[0];
    const float* Wa = (const float*)d_in[1];
    const float* ba = (const float*)d_in[2];
    const float* Wg = (const float*)d_in[3];
    const float* bg = (const float*)d_in[4];
    const float* Wu = (const float*)d_in[5];
    const float* bu = (const float*)d_in[6];
    const float* u  = (const float*)d_in[7];
    const float* v  = (const float*)d_in[8];
    float* out = (float*)d_out;

    char* ws = (char*)d_ws;
    unsigned short* xb   = (unsigned short*)(ws);                // 67,108,864 B
    unsigned short* Wab  = (unsigned short*)(ws + 67108864);     //  2,097,152 B
    unsigned short* Wub  = (unsigned short*)(ws + 69206016);     //  2,097,152 B
    unsigned short* abuf = (unsigned short*)(ws + 71303168);     // 67,108,864 B (bf16)
    unsigned short* ubuf = (unsigned short*)(ws + 138412032);    // 67,108,864 B (bf16)
    float*          gbuf = (float*)(ws + 205520896);             //  2,097,152 B

    hipLaunchKernelGGL(k_convert, dim3(34816), dim3(256), 0, stream,
                       x, Wa, Wu, xb, Wab, Wub);
    hipLaunchKernelGGL(k_gemm, dim3(256, 16), dim3(256), 0, stream,
                       xb, Wab, Wub, ba, bu, abuf, ubuf);
    hipLaunchKernelGGL(k_g, dim3(2048), dim3(256), 0, stream,
                       x, Wg, bg, gbuf);
    hipLaunchKernelGGL(k_scan, dim3(Bb), dim3(1024), 0, stream,
                       abuf, ubuf, gbuf, u, v, out);
}